// Round 8
// baseline (24367.574 us; speedup 1.0000x reference)
//
#include <hip/hip_runtime.h>
#include <hip/hip_fp16.h>

// ---------------------------------------------------------------------------
// AttentionEncoder: B=256, T=512, D=64, H=128
// rnn kernel: 1 block per b, 512 threads. Weights are packed f16 pairs and
// STREAMED from L2 every step (56 dwordx4 loads/thread/step, grouped for
// ILP). Rounds 4-7 proved the register allocator caps this kernel at 128
// VGPRs and spills any register-resident weight set to scratch (37 GB HBM,
// 24-44 ms) -- so we stop fighting it. L2 roofline: 448 KB/step/CU at
// ~57 B/cyc/CU -> ~1.7 ms.
// Phase-2 exact-math trims: s1,s2 pre-scaled by 2 (kills inner mul of
// tanh), and e[d] computed as sum of (-2*w3)*rcp(exp+1) -- the w3-sum and
// b3 constants cancel in softmax.
// ---------------------------------------------------------------------------

__device__ __forceinline__ float sigm(float x) {
  return __builtin_amdgcn_rcpf(1.f + __expf(-x));
}
__device__ __forceinline__ float tanh_fast(float x) {
  float e = __expf(2.f * x);
  return fmaf(-2.f, __builtin_amdgcn_rcpf(e + 1.f), 1.f);
}
__device__ __forceinline__ unsigned pack2(float a, float b) {
  unsigned lo = __half_as_ushort(__float2half(a));
  unsigned hi = __half_as_ushort(__float2half(b));
  return lo | (hi << 16);
}
// by-value f16 unpack; fmaf(f16->f32, f32, f32) maps to v_fma_mix_f32.
__device__ __forceinline__ float h2lo(unsigned u) {
  return __half2float(__ushort_as_half((unsigned short)(u & 0xffffu)));
}
__device__ __forceinline__ float h2hi(unsigned u) {
  return __half2float(__ushort_as_half((unsigned short)(u >> 16)));
}

// ---- pack weights to f16 + fuse biases ------------------------------------
// W1P[k4*512 + t] (uint4) holds f16 W1[t][8k4 .. 8k4+7]   (k4 in [0,32))
// WZP[k4*512 + t] (uint4) holds f16 WZ[t][8k4 .. 8k4+7]   (k4 in [0,24))
//   where WZ[t][c] = c<64 ? Wih[t][c] : Whh[t][c-64]
__global__ __launch_bounds__(256) void pack_kernel(
    const float* __restrict__ W1, const float* __restrict__ Wih,
    const float* __restrict__ Whh, const float* __restrict__ bih,
    const float* __restrict__ bhh, uint4* __restrict__ W1P,
    uint4* __restrict__ WZP, float* __restrict__ bz) {
  int gid = blockIdx.x * 256 + threadIdx.x;
  if (gid < 512) bz[gid] = bih[gid] + bhh[gid];
  if (gid < 16384) {
    int k4 = gid >> 9, t = gid & 511;
    const float* src = W1 + t * 256 + k4 * 8;
    uint4 o;
    o.x = pack2(src[0], src[1]);
    o.y = pack2(src[2], src[3]);
    o.z = pack2(src[4], src[5]);
    o.w = pack2(src[6], src[7]);
    W1P[gid] = o;
  } else if (gid < 28672) {
    int g = gid - 16384;
    int k4 = g >> 9, t = g & 511;
    float v[8];
#pragma unroll
    for (int q = 0; q < 8; ++q) {
      int col = k4 * 8 + q;
      v[q] = (col < 64) ? Wih[t * 64 + col] : Whh[t * 128 + col - 64];
    }
    uint4 o;
    o.x = pack2(v[0], v[1]);
    o.y = pack2(v[2], v[3]);
    o.z = pack2(v[4], v[5]);
    o.w = pack2(v[6], v[7]);
    WZP[g] = o;
  }
}

// ---- s2 = einsum('btd,st->bds') + b2 --------------------------------------
__global__ __launch_bounds__(256) void s2_kernel(
    const float* __restrict__ X, const float* __restrict__ W2,
    const float* __restrict__ b2, float* __restrict__ s2) {
  __shared__ float Xs[64 * 68];
  __shared__ float W2sT[64 * 68];
  const int b = blockIdx.y;
  const int s0 = blockIdx.x * 64;
  const int tid = threadIdx.x;
  const int dq = tid & 15, sq = tid >> 4;
  float acc[4][4] = {{0.f, 0.f, 0.f, 0.f}};

  for (int t0 = 0; t0 < 512; t0 += 64) {
    __syncthreads();
    for (int i = tid; i < 4096; i += 256) {
      int tt = i >> 6, dd = i & 63;
      Xs[tt * 68 + dd] = X[((size_t)b * 512 + t0 + tt) * 64 + dd];
      int ss = i >> 6, t2 = i & 63;
      W2sT[t2 * 68 + ss] = W2[(size_t)(s0 + ss) * 512 + t0 + t2];
    }
    __syncthreads();
    const float4* Xs4 = (const float4*)Xs;
    const float4* W4 = (const float4*)W2sT;
#pragma unroll 8
    for (int tt = 0; tt < 64; ++tt) {
      float4 xv = Xs4[tt * 17 + dq];
      float4 wv = W4[tt * 17 + sq];
      float xa[4] = {xv.x, xv.y, xv.z, xv.w};
      float wa[4] = {wv.x, wv.y, wv.z, wv.w};
#pragma unroll
      for (int q = 0; q < 4; ++q)
#pragma unroll
        for (int r = 0; r < 4; ++r) acc[q][r] += xa[q] * wa[r];
    }
  }
  const float* bp = b2 + s0 + sq * 4;
  float b0 = bp[0], bx1 = bp[1], bx2 = bp[2], bx3 = bp[3];
#pragma unroll
  for (int q = 0; q < 4; ++q) {
    float4 o = make_float4(acc[q][0] + b0, acc[q][1] + bx1,
                           acc[q][2] + bx2, acc[q][3] + bx3);
    *(float4*)&s2[((size_t)b * 64 + dq * 4 + q) * 512 + s0 + sq * 4] = o;
  }
}

// ---- the recurrence -------------------------------------------------------
// grid 256 (one block per b), 512 threads.
__global__ __launch_bounds__(512) void rnn_kernel(
    const float* __restrict__ X, const float* __restrict__ s2g,
    const uint4* __restrict__ W1P, const uint4* __restrict__ WZP,
    const float* __restrict__ b1, const float* __restrict__ bz,
    const float* __restrict__ W3, float* __restrict__ out) {
  __shared__ float4 s2s4[64 * 128];  // 128 KB: 2*s2[b], row d = 512 f32
  __shared__ float4 hc4[64];         // [h(128); c(128)]
  __shared__ float4 xh4[48];         // [x(64); h(128)]
  __shared__ float4 s1s4[128];       // 2*s1 (512)
  __shared__ float4 w3s4[128];       // -2*w3 (512)
  __shared__ float eb[64];
  __shared__ float zb[512];

  float* hc = (float*)hc4;
  float* xh = (float*)xh4;
  float* s1s = (float*)s1s4;
  float* w3s = (float*)w3s4;

  const int b = blockIdx.x;
  const int tid = threadIdx.x;
  const int lane = tid & 63;
  const int w = tid >> 6;

  // ---- stage 2*s2[b] into LDS (pre-scaled for the tanh exp) ----
  {
    const float4* src = (const float4*)(s2g + (size_t)b * 32768);
    for (int i = tid; i < 8192; i += 512) {
      float4 v = src[i];
      s2s4[i] = make_float4(2.f * v.x, 2.f * v.y, 2.f * v.z, 2.f * v.w);
    }
  }
  if (tid < 64) hc4[tid] = make_float4(0.f, 0.f, 0.f, 0.f);
  if (tid >= 64 && tid < 112) xh4[tid - 64] = make_float4(0.f, 0.f, 0.f, 0.f);
  w3s[tid] = -2.f * W3[tid];
  const float b1r = b1[tid];
  const float bzr = bz[tid];
  float xpre = X[((size_t)b * 512 + 0) * 64 + lane];

  const uint4* w1t = W1P + tid;   // thread's W1 row, stride 512 uint4 per k
  const uint4* wzt = WZP + tid;
  __syncthreads();

  for (int t = 0; t < 512; ++t) {
    // ---- phase 1: s1[tid] = [h;c] . W1[tid,:] + b1  (weights streamed) ----
    float a0 = b1r, a1 = 0.f, a2 = 0.f, a3 = 0.f;
#define FMA8(Q, K, A) {                        \
    const float4 ha = hc4[2 * (K)];            \
    const float4 hb = hc4[2 * (K) + 1];        \
    A = fmaf(h2lo(Q.x), ha.x, A);              \
    A = fmaf(h2hi(Q.x), ha.y, A);              \
    A = fmaf(h2lo(Q.y), ha.z, A);              \
    A = fmaf(h2hi(Q.y), ha.w, A);              \
    A = fmaf(h2lo(Q.z), hb.x, A);              \
    A = fmaf(h2hi(Q.z), hb.y, A);              \
    A = fmaf(h2lo(Q.w), hb.z, A);              \
    A = fmaf(h2hi(Q.w), hb.w, A);              \
  }
#define P1G(G) {                               \
    const uint4 q0 = w1t[((G) * 8 + 0) * 512]; \
    const uint4 q1 = w1t[((G) * 8 + 1) * 512]; \
    const uint4 q2 = w1t[((G) * 8 + 2) * 512]; \
    const uint4 q3 = w1t[((G) * 8 + 3) * 512]; \
    const uint4 q4 = w1t[((G) * 8 + 4) * 512]; \
    const uint4 q5 = w1t[((G) * 8 + 5) * 512]; \
    const uint4 q6 = w1t[((G) * 8 + 6) * 512]; \
    const uint4 q7 = w1t[((G) * 8 + 7) * 512]; \
    FMA8(q0, (G) * 8 + 0, a0)                  \
    FMA8(q1, (G) * 8 + 1, a1)                  \
    FMA8(q2, (G) * 8 + 2, a2)                  \
    FMA8(q3, (G) * 8 + 3, a3)                  \
    FMA8(q4, (G) * 8 + 4, a0)                  \
    FMA8(q5, (G) * 8 + 5, a1)                  \
    FMA8(q6, (G) * 8 + 6, a2)                  \
    FMA8(q7, (G) * 8 + 7, a3)                  \
  }
    P1G(0) P1G(1) P1G(2) P1G(3)
    s1s[tid] = 2.f * ((a0 + a1) + (a2 + a3));  // pre-scaled by 2
    __syncthreads();

    // ---- phase 2: eb[d] = sum_t (-2*w3_t) * rcp(exp(2*(s1+s2)) + 1) ----
    // (w3-sum and b3 constants dropped -- softmax shift-invariant)
    {
      float l0 = 0.f, l1 = 0.f, l2 = 0.f, l3 = 0.f;
      float l4 = 0.f, l5 = 0.f, l6 = 0.f, l7 = 0.f;
#define P2D(DD, L) {                                                     \
      const float4 s2v = rowp[(DD) * 1024];                              \
      L = fmaf(wv.x, __builtin_amdgcn_rcpf(__expf(sv.x + s2v.x) + 1.f), L); \
      L = fmaf(wv.y, __builtin_amdgcn_rcpf(__expf(sv.y + s2v.y) + 1.f), L); \
      L = fmaf(wv.z, __builtin_amdgcn_rcpf(__expf(sv.z + s2v.z) + 1.f), L); \
      L = fmaf(wv.w, __builtin_amdgcn_rcpf(__expf(sv.w + s2v.w) + 1.f), L); \
    }
#pragma unroll
      for (int i = 0; i < 2; ++i) {
        const int f4 = lane + 64 * i;
        const float4 sv = s1s4[f4];
        const float4 wv = w3s4[f4];
        const float4* rowp = &s2s4[w * 128 + f4];
        P2D(0, l0) P2D(1, l1) P2D(2, l2) P2D(3, l3)
        P2D(4, l4) P2D(5, l5) P2D(6, l6) P2D(7, l7)
      }
#define P2R(DD, L) {                                                     \
      float local = L;                                                   \
      _Pragma("unroll")                                                  \
      for (int off = 32; off; off >>= 1) local += __shfl_xor(local, off);\
      if (lane == 0) eb[w + 8 * (DD)] = local;                           \
    }
      P2R(0, l0) P2R(1, l1) P2R(2, l2) P2R(3, l3)
      P2R(4, l4) P2R(5, l5) P2R(6, l6) P2R(7, l7)
    }
    __syncthreads();

    // ---- phase 3: softmax over d (64) + x = a * x_t  (wave 0 only) ----
    if (w == 0) {
      float e = eb[lane];
      float m = e;
#pragma unroll
      for (int off = 32; off; off >>= 1) m = fmaxf(m, __shfl_xor(m, off));
      float p = __expf(e - m);
      float s = p;
#pragma unroll
      for (int off = 32; off; off >>= 1) s += __shfl_xor(s, off);
      xh[lane] = __builtin_amdgcn_rcpf(s) * p * xpre;
      int tn = (t + 1 < 512) ? t + 1 : 511;
      xpre = X[((size_t)b * 512 + tn) * 64 + lane];
    }
    __syncthreads();

    // ---- phase 4: z[tid] = [x;h] . WZ[tid,:] + bz  (weights streamed) ----
    float z0 = bzr, z1 = 0.f, z2 = 0.f, z3 = 0.f;
#define FMZ8(Q, K, A) {                        \
    const float4 xa = xh4[2 * (K)];            \
    const float4 xb = xh4[2 * (K) + 1];        \
    A = fmaf(h2lo(Q.x), xa.x, A);              \
    A = fmaf(h2hi(Q.x), xa.y, A);              \
    A = fmaf(h2lo(Q.y), xa.z, A);              \
    A = fmaf(h2hi(Q.y), xa.w, A);              \
    A = fmaf(h2lo(Q.z), xb.x, A);              \
    A = fmaf(h2hi(Q.z), xb.y, A);              \
    A = fmaf(h2lo(Q.w), xb.z, A);              \
    A = fmaf(h2hi(Q.w), xb.w, A);              \
  }
#define P4G(G) {                               \
    const uint4 q0 = wzt[((G) * 8 + 0) * 512]; \
    const uint4 q1 = wzt[((G) * 8 + 1) * 512]; \
    const uint4 q2 = wzt[((G) * 8 + 2) * 512]; \
    const uint4 q3 = wzt[((G) * 8 + 3) * 512]; \
    const uint4 q4 = wzt[((G) * 8 + 4) * 512]; \
    const uint4 q5 = wzt[((G) * 8 + 5) * 512]; \
    const uint4 q6 = wzt[((G) * 8 + 6) * 512]; \
    const uint4 q7 = wzt[((G) * 8 + 7) * 512]; \
    FMZ8(q0, (G) * 8 + 0, z0)                  \
    FMZ8(q1, (G) * 8 + 1, z1)                  \
    FMZ8(q2, (G) * 8 + 2, z2)                  \
    FMZ8(q3, (G) * 8 + 3, z3)                  \
    FMZ8(q4, (G) * 8 + 4, z0)                  \
    FMZ8(q5, (G) * 8 + 5, z1)                  \
    FMZ8(q6, (G) * 8 + 6, z2)                  \
    FMZ8(q7, (G) * 8 + 7, z3)                  \
  }
    P4G(0) P4G(1) P4G(2)
    zb[tid] = (z0 + z1) + (z2 + z3);
    __syncthreads();

    // ---- phase 5: LSTM gates, write h ----
    if (tid < 128) {
      float iv = zb[tid], fv = zb[tid + 128], gv = zb[tid + 256], ov = zb[tid + 384];
      float c = hc[128 + tid];
      float cn = sigm(fv) * c + sigm(iv) * tanh_fast(gv);
      float hn = sigm(ov) * tanh_fast(cn);
      hc[tid] = hn;
      hc[128 + tid] = cn;
      xh[64 + tid] = hn;
      out[((size_t)b * 512 + t) * 128 + tid] = hn;
    }
    __syncthreads();
  }
}

extern "C" void kernel_launch(void* const* d_in, const int* in_sizes, int n_in,
                              void* d_out, int out_size, void* d_ws, size_t ws_size,
                              hipStream_t stream) {
  const float* X   = (const float*)d_in[0];
  const float* Wih = (const float*)d_in[1];
  const float* Whh = (const float*)d_in[2];
  const float* bih = (const float*)d_in[3];
  const float* bhh = (const float*)d_in[4];
  const float* W1  = (const float*)d_in[5];
  const float* b1  = (const float*)d_in[6];
  const float* W2  = (const float*)d_in[7];
  const float* b2  = (const float*)d_in[8];
  const float* W3  = (const float*)d_in[9];
  float* out = (float*)d_out;
  float* ws = (float*)d_ws;

  float* s2  = ws;                               // 8,388,608 f32 (32 MB)
  uint4* W1P = (uint4*)(ws + 8388608);           // 16384 uint4 (256 KB)
  uint4* WZP = (uint4*)(ws + 8388608 + 65536);   // 12288 uint4 (192 KB)
  float* bz  = ws + 8388608 + 65536 + 49152;     // 512 f32

  hipLaunchKernelGGL(pack_kernel, dim3(112), dim3(256), 0, stream,
                     W1, Wih, Whh, bih, bhh, W1P, WZP, bz);
  hipLaunchKernelGGL(s2_kernel, dim3(8, 256), dim3(256), 0, stream,
                     X, W2, b2, s2);
  hipLaunchKernelGGL(rnn_kernel, dim3(256), dim3(512), 0, stream,
                     X, s2, W1P, WZP, b1, bz, W3, out);
}

// Round 9
// 5020.847 us; speedup vs baseline: 4.8533x; 4.8533x over previous
//
#include <hip/hip_runtime.h>
#include <hip/hip_fp16.h>

// ---------------------------------------------------------------------------
// AttentionEncoder: B=256, T=512, D=64, H=128
// rnn kernel: 1 block per b, 512 threads. Weights are packed f16 pairs
// streamed from L2 every step. Rounds 4-8 post-mortem: ANY formulation that
// lets the weights become loop-invariant register values (explicit preload
// OR compiler LICM of in-loop loads) ends at VGPR=128 + 37 GB scratch
// re-reads + ~27 ms. Fix here: per-iteration opaque zero offset
// (asm volatile "+v") makes the load addresses formally loop-variant, so
// LICM cannot hoist; loads execute per-step and hit the L2-resident 448 KB
// weight set. L2 roofline ~8.1 K cyc/step/CU -> ~2 ms.
// ---------------------------------------------------------------------------

__device__ __forceinline__ float sigm(float x) {
  return __builtin_amdgcn_rcpf(1.f + __expf(-x));
}
__device__ __forceinline__ float tanh_fast(float x) {
  float e = __expf(2.f * x);
  return fmaf(-2.f, __builtin_amdgcn_rcpf(e + 1.f), 1.f);
}
__device__ __forceinline__ unsigned pack2(float a, float b) {
  unsigned lo = __half_as_ushort(__float2half(a));
  unsigned hi = __half_as_ushort(__float2half(b));
  return lo | (hi << 16);
}
// by-value f16 unpack; fmaf(f16->f32, f32, f32) maps to v_fma_mix_f32.
__device__ __forceinline__ float h2lo(unsigned u) {
  return __half2float(__ushort_as_half((unsigned short)(u & 0xffffu)));
}
__device__ __forceinline__ float h2hi(unsigned u) {
  return __half2float(__ushort_as_half((unsigned short)(u >> 16)));
}

// ---- pack weights to f16 + fuse biases ------------------------------------
// W1P[k4*512 + t] (uint4) holds f16 W1[t][8k4 .. 8k4+7]   (k4 in [0,32))
// WZP[k4*512 + t] (uint4) holds f16 WZ[t][8k4 .. 8k4+7]   (k4 in [0,24))
//   where WZ[t][c] = c<64 ? Wih[t][c] : Whh[t][c-64]
__global__ __launch_bounds__(256) void pack_kernel(
    const float* __restrict__ W1, const float* __restrict__ Wih,
    const float* __restrict__ Whh, const float* __restrict__ bih,
    const float* __restrict__ bhh, uint4* __restrict__ W1P,
    uint4* __restrict__ WZP, float* __restrict__ bz) {
  int gid = blockIdx.x * 256 + threadIdx.x;
  if (gid < 512) bz[gid] = bih[gid] + bhh[gid];
  if (gid < 16384) {
    int k4 = gid >> 9, t = gid & 511;
    const float* src = W1 + t * 256 + k4 * 8;
    uint4 o;
    o.x = pack2(src[0], src[1]);
    o.y = pack2(src[2], src[3]);
    o.z = pack2(src[4], src[5]);
    o.w = pack2(src[6], src[7]);
    W1P[gid] = o;
  } else if (gid < 28672) {
    int g = gid - 16384;
    int k4 = g >> 9, t = g & 511;
    float v[8];
#pragma unroll
    for (int q = 0; q < 8; ++q) {
      int col = k4 * 8 + q;
      v[q] = (col < 64) ? Wih[t * 64 + col] : Whh[t * 128 + col - 64];
    }
    uint4 o;
    o.x = pack2(v[0], v[1]);
    o.y = pack2(v[2], v[3]);
    o.z = pack2(v[4], v[5]);
    o.w = pack2(v[6], v[7]);
    WZP[g] = o;
  }
}

// ---- s2 = einsum('btd,st->bds') + b2 --------------------------------------
__global__ __launch_bounds__(256) void s2_kernel(
    const float* __restrict__ X, const float* __restrict__ W2,
    const float* __restrict__ b2, float* __restrict__ s2) {
  __shared__ float Xs[64 * 68];
  __shared__ float W2sT[64 * 68];
  const int b = blockIdx.y;
  const int s0 = blockIdx.x * 64;
  const int tid = threadIdx.x;
  const int dq = tid & 15, sq = tid >> 4;
  float acc[4][4] = {{0.f, 0.f, 0.f, 0.f}};

  for (int t0 = 0; t0 < 512; t0 += 64) {
    __syncthreads();
    for (int i = tid; i < 4096; i += 256) {
      int tt = i >> 6, dd = i & 63;
      Xs[tt * 68 + dd] = X[((size_t)b * 512 + t0 + tt) * 64 + dd];
      int ss = i >> 6, t2 = i & 63;
      W2sT[t2 * 68 + ss] = W2[(size_t)(s0 + ss) * 512 + t0 + t2];
    }
    __syncthreads();
    const float4* Xs4 = (const float4*)Xs;
    const float4* W4 = (const float4*)W2sT;
#pragma unroll 8
    for (int tt = 0; tt < 64; ++tt) {
      float4 xv = Xs4[tt * 17 + dq];
      float4 wv = W4[tt * 17 + sq];
      float xa[4] = {xv.x, xv.y, xv.z, xv.w};
      float wa[4] = {wv.x, wv.y, wv.z, wv.w};
#pragma unroll
      for (int q = 0; q < 4; ++q)
#pragma unroll
        for (int r = 0; r < 4; ++r) acc[q][r] += xa[q] * wa[r];
    }
  }
  const float* bp = b2 + s0 + sq * 4;
  float b0 = bp[0], bx1 = bp[1], bx2 = bp[2], bx3 = bp[3];
#pragma unroll
  for (int q = 0; q < 4; ++q) {
    float4 o = make_float4(acc[q][0] + b0, acc[q][1] + bx1,
                           acc[q][2] + bx2, acc[q][3] + bx3);
    *(float4*)&s2[((size_t)b * 64 + dq * 4 + q) * 512 + s0 + sq * 4] = o;
  }
}

// ---- the recurrence -------------------------------------------------------
// grid 256 (one block per b), 512 threads.
__global__ __launch_bounds__(512) void rnn_kernel(
    const float* __restrict__ X, const float* __restrict__ s2g,
    const uint4* __restrict__ W1P, const uint4* __restrict__ WZP,
    const float* __restrict__ b1, const float* __restrict__ bz,
    const float* __restrict__ W3, float* __restrict__ out) {
  __shared__ float4 s2s4[64 * 128];  // 128 KB: 2*s2[b], row d = 512 f32
  __shared__ float4 hc4[64];         // [h(128); c(128)]
  __shared__ float4 xh4[48];         // [x(64); h(128)]
  __shared__ float4 s1s4[128];       // 2*s1 (512)
  __shared__ float4 w3s4[128];       // -2*w3 (512)
  __shared__ float eb[64];
  __shared__ float zb[512];

  float* hc = (float*)hc4;
  float* xh = (float*)xh4;
  float* s1s = (float*)s1s4;
  float* w3s = (float*)w3s4;

  const int b = blockIdx.x;
  const int tid = threadIdx.x;
  const int lane = tid & 63;
  const int w = tid >> 6;

  // ---- stage 2*s2[b] into LDS (pre-scaled for the tanh exp) ----
  {
    const float4* src = (const float4*)(s2g + (size_t)b * 32768);
    for (int i = tid; i < 8192; i += 512) {
      float4 v = src[i];
      s2s4[i] = make_float4(2.f * v.x, 2.f * v.y, 2.f * v.z, 2.f * v.w);
    }
  }
  if (tid < 64) hc4[tid] = make_float4(0.f, 0.f, 0.f, 0.f);
  if (tid >= 64 && tid < 112) xh4[tid - 64] = make_float4(0.f, 0.f, 0.f, 0.f);
  w3s[tid] = -2.f * W3[tid];
  const float b1r = b1[tid];
  const float bzr = bz[tid];
  float xpre = X[((size_t)b * 512 + 0) * 64 + lane];
  __syncthreads();

  for (int t = 0; t < 512; ++t) {
    // Opaque zero offset: formally loop-variant address -> LICM cannot hoist
    // the weight loads out of the t-loop (rounds 4-8: hoist -> spill -> 37 GB
    // scratch traffic). Costs two address adds per iteration.
    unsigned zoff = 0;
    asm volatile("" : "+v"(zoff));
    const uint4* w1t = W1P + tid + zoff;
    const uint4* wzt = WZP + tid + zoff;

    // ---- phase 1: s1[tid] = [h;c] . W1[tid,:] + b1  (weights streamed) ----
    float a0 = b1r, a1 = 0.f, a2 = 0.f, a3 = 0.f;
#define FMA8(Q, K, A) {                        \
    const float4 ha = hc4[2 * (K)];            \
    const float4 hb = hc4[2 * (K) + 1];        \
    A = fmaf(h2lo(Q.x), ha.x, A);              \
    A = fmaf(h2hi(Q.x), ha.y, A);              \
    A = fmaf(h2lo(Q.y), ha.z, A);              \
    A = fmaf(h2hi(Q.y), ha.w, A);              \
    A = fmaf(h2lo(Q.z), hb.x, A);              \
    A = fmaf(h2hi(Q.z), hb.y, A);              \
    A = fmaf(h2lo(Q.w), hb.z, A);              \
    A = fmaf(h2hi(Q.w), hb.w, A);              \
  }
#define P1G(G) {                               \
    const uint4 q0 = w1t[((G) * 8 + 0) * 512]; \
    const uint4 q1 = w1t[((G) * 8 + 1) * 512]; \
    const uint4 q2 = w1t[((G) * 8 + 2) * 512]; \
    const uint4 q3 = w1t[((G) * 8 + 3) * 512]; \
    const uint4 q4 = w1t[((G) * 8 + 4) * 512]; \
    const uint4 q5 = w1t[((G) * 8 + 5) * 512]; \
    const uint4 q6 = w1t[((G) * 8 + 6) * 512]; \
    const uint4 q7 = w1t[((G) * 8 + 7) * 512]; \
    FMA8(q0, (G) * 8 + 0, a0)                  \
    FMA8(q1, (G) * 8 + 1, a1)                  \
    FMA8(q2, (G) * 8 + 2, a2)                  \
    FMA8(q3, (G) * 8 + 3, a3)                  \
    FMA8(q4, (G) * 8 + 4, a0)                  \
    FMA8(q5, (G) * 8 + 5, a1)                  \
    FMA8(q6, (G) * 8 + 6, a2)                  \
    FMA8(q7, (G) * 8 + 7, a3)                  \
  }
    P1G(0) P1G(1) P1G(2) P1G(3)
    s1s[tid] = 2.f * ((a0 + a1) + (a2 + a3));  // pre-scaled by 2
    __syncthreads();

    // ---- phase 2: eb[d] = sum_t (-2*w3_t) * rcp(exp(2*(s1+s2)) + 1) ----
    // (w3-sum and b3 constants dropped -- softmax shift-invariant)
    {
      float l0 = 0.f, l1 = 0.f, l2 = 0.f, l3 = 0.f;
      float l4 = 0.f, l5 = 0.f, l6 = 0.f, l7 = 0.f;
#define P2D(DD, L) {                                                     \
      const float4 s2v = rowp[(DD) * 1024];                              \
      L = fmaf(wv.x, __builtin_amdgcn_rcpf(__expf(sv.x + s2v.x) + 1.f), L); \
      L = fmaf(wv.y, __builtin_amdgcn_rcpf(__expf(sv.y + s2v.y) + 1.f), L); \
      L = fmaf(wv.z, __builtin_amdgcn_rcpf(__expf(sv.z + s2v.z) + 1.f), L); \
      L = fmaf(wv.w, __builtin_amdgcn_rcpf(__expf(sv.w + s2v.w) + 1.f), L); \
    }
#pragma unroll
      for (int i = 0; i < 2; ++i) {
        const int f4 = lane + 64 * i;
        const float4 sv = s1s4[f4];
        const float4 wv = w3s4[f4];
        const float4* rowp = &s2s4[w * 128 + f4];
        P2D(0, l0) P2D(1, l1) P2D(2, l2) P2D(3, l3)
        P2D(4, l4) P2D(5, l5) P2D(6, l6) P2D(7, l7)
      }
#define P2R(DD, L) {                                                     \
      float local = L;                                                   \
      _Pragma("unroll")                                                  \
      for (int off = 32; off; off >>= 1) local += __shfl_xor(local, off);\
      if (lane == 0) eb[w + 8 * (DD)] = local;                           \
    }
      P2R(0, l0) P2R(1, l1) P2R(2, l2) P2R(3, l3)
      P2R(4, l4) P2R(5, l5) P2R(6, l6) P2R(7, l7)
    }
    __syncthreads();

    // ---- phase 3: softmax over d (64) + x = a * x_t  (wave 0 only) ----
    if (w == 0) {
      float e = eb[lane];
      float m = e;
#pragma unroll
      for (int off = 32; off; off >>= 1) m = fmaxf(m, __shfl_xor(m, off));
      float p = __expf(e - m);
      float s = p;
#pragma unroll
      for (int off = 32; off; off >>= 1) s += __shfl_xor(s, off);
      xh[lane] = __builtin_amdgcn_rcpf(s) * p * xpre;
      int tn = (t + 1 < 512) ? t + 1 : 511;
      xpre = X[((size_t)b * 512 + tn) * 64 + lane];
    }
    __syncthreads();

    // ---- phase 4: z[tid] = [x;h] . WZ[tid,:] + bz  (weights streamed) ----
    float z0 = bzr, z1 = 0.f, z2 = 0.f, z3 = 0.f;
#define FMZ8(Q, K, A) {                        \
    const float4 xa = xh4[2 * (K)];            \
    const float4 xb = xh4[2 * (K) + 1];        \
    A = fmaf(h2lo(Q.x), xa.x, A);              \
    A = fmaf(h2hi(Q.x), xa.y, A);              \
    A = fmaf(h2lo(Q.y), xa.z, A);              \
    A = fmaf(h2hi(Q.y), xa.w, A);              \
    A = fmaf(h2lo(Q.z), xb.x, A);              \
    A = fmaf(h2hi(Q.z), xb.y, A);              \
    A = fmaf(h2lo(Q.w), xb.z, A);              \
    A = fmaf(h2hi(Q.w), xb.w, A);              \
  }
#define P4G(G) {                               \
    const uint4 q0 = wzt[((G) * 8 + 0) * 512]; \
    const uint4 q1 = wzt[((G) * 8 + 1) * 512]; \
    const uint4 q2 = wzt[((G) * 8 + 2) * 512]; \
    const uint4 q3 = wzt[((G) * 8 + 3) * 512]; \
    const uint4 q4 = wzt[((G) * 8 + 4) * 512]; \
    const uint4 q5 = wzt[((G) * 8 + 5) * 512]; \
    const uint4 q6 = wzt[((G) * 8 + 6) * 512]; \
    const uint4 q7 = wzt[((G) * 8 + 7) * 512]; \
    FMZ8(q0, (G) * 8 + 0, z0)                  \
    FMZ8(q1, (G) * 8 + 1, z1)                  \
    FMZ8(q2, (G) * 8 + 2, z2)                  \
    FMZ8(q3, (G) * 8 + 3, z3)                  \
    FMZ8(q4, (G) * 8 + 4, z0)                  \
    FMZ8(q5, (G) * 8 + 5, z1)                  \
    FMZ8(q6, (G) * 8 + 6, z2)                  \
    FMZ8(q7, (G) * 8 + 7, z3)                  \
  }
    P4G(0) P4G(1) P4G(2)
    zb[tid] = (z0 + z1) + (z2 + z3);
    __syncthreads();

    // ---- phase 5: LSTM gates, write h ----
    if (tid < 128) {
      float iv = zb[tid], fv = zb[tid + 128], gv = zb[tid + 256], ov = zb[tid + 384];
      float c = hc[128 + tid];
      float cn = sigm(fv) * c + sigm(iv) * tanh_fast(gv);
      float hn = sigm(ov) * tanh_fast(cn);
      hc[tid] = hn;
      hc[128 + tid] = cn;
      xh[64 + tid] = hn;
      out[((size_t)b * 512 + t) * 128 + tid] = hn;
    }
    __syncthreads();
  }
}

extern "C" void kernel_launch(void* const* d_in, const int* in_sizes, int n_in,
                              void* d_out, int out_size, void* d_ws, size_t ws_size,
                              hipStream_t stream) {
  const float* X   = (const float*)d_in[0];
  const float* Wih = (const float*)d_in[1];
  const float* Whh = (const float*)d_in[2];
  const float* bih = (const float*)d_in[3];
  const float* bhh = (const float*)d_in[4];
  const float* W1  = (const float*)d_in[5];
  const float* b1  = (const float*)d_in[6];
  const float* W2  = (const float*)d_in[7];
  const float* b2  = (const float*)d_in[8];
  const float* W3  = (const float*)d_in[9];
  float* out = (float*)d_out;
  float* ws = (float*)d_ws;

  float* s2  = ws;                               // 8,388,608 f32 (32 MB)
  uint4* W1P = (uint4*)(ws + 8388608);           // 16384 uint4 (256 KB)
  uint4* WZP = (uint4*)(ws + 8388608 + 65536);   // 12288 uint4 (192 KB)
  float* bz  = ws + 8388608 + 65536 + 49152;     // 512 f32

  hipLaunchKernelGGL(pack_kernel, dim3(112), dim3(256), 0, stream,
                     W1, Wih, Whh, bih, bhh, W1P, WZP, bz);
  hipLaunchKernelGGL(s2_kernel, dim3(8, 256), dim3(256), 0, stream,
                     X, W2, b2, s2);
  hipLaunchKernelGGL(rnn_kernel, dim3(256), dim3(512), 0, stream,
                     X, s2, W1P, WZP, b1, bz, W3, out);
}

// Round 10
// 5011.201 us; speedup vs baseline: 4.8626x; 1.0019x over previous
//
#include <hip/hip_runtime.h>
#include <hip/hip_fp16.h>

// ---------------------------------------------------------------------------
// AttentionEncoder: B=256, T=512, D=64, H=128
// rnn kernel v3: 1 block per b, 1024 threads (16 waves = 4/SIMD for latency
// hiding; round-9 showed 2 waves/SIMD left ~75% stall time). Phases 1/4 are
// split-k (two 128/96-col halves per row, partials combined via LDS).
// Weights stream from L2 as f16 pairs (zoff blocks LICM re-hoist -> round-4/6
// spill disaster). MACs use v_dot2_f32_f16 (1 inst / 2 MACs); activations
// packed to f16 pairs in LDS at producer time. Phase 2 uses exp2 with
// pre-scaled (2*log2e) s1/s2. Softmax computed redundantly by all waves
// (identical benign writes) -- saves a barrier. 4 barriers/step.
// ---------------------------------------------------------------------------

#define SCALE2F 2.885390081777927f  // 2*log2(e)

typedef _Float16 h2v __attribute__((ext_vector_type(2)));

__device__ __forceinline__ float h2lo(unsigned u) {
  return __half2float(__ushort_as_half((unsigned short)(u & 0xffffu)));
}
__device__ __forceinline__ float h2hi(unsigned u) {
  return __half2float(__ushort_as_half((unsigned short)(u >> 16)));
}
__device__ __forceinline__ float dot2(unsigned w, unsigned a, float acc) {
#if __has_builtin(__builtin_amdgcn_fdot2)
  return __builtin_amdgcn_fdot2(__builtin_bit_cast(h2v, w),
                                __builtin_bit_cast(h2v, a), acc, false);
#else
  return fmaf(h2lo(w), h2lo(a), fmaf(h2hi(w), h2hi(a), acc));
#endif
}
__device__ __forceinline__ float dot4q(uint4 w, uint4 a, float acc) {
  acc = dot2(w.x, a.x, acc);
  acc = dot2(w.y, a.y, acc);
  acc = dot2(w.z, a.z, acc);
  acc = dot2(w.w, a.w, acc);
  return acc;
}
__device__ __forceinline__ float sigm(float x) {
  return __builtin_amdgcn_rcpf(1.f + __expf(-x));
}
__device__ __forceinline__ float tanh_fast(float x) {
  float e = __expf(2.f * x);
  return fmaf(-2.f, __builtin_amdgcn_rcpf(e + 1.f), 1.f);
}
__device__ __forceinline__ unsigned pack2(float a, float b) {
  unsigned lo = __half_as_ushort(__float2half(a));
  unsigned hi = __half_as_ushort(__float2half(b));
  return lo | (hi << 16);
}

// ---- pack weights to f16 + fuse biases ------------------------------------
// W1P[k4*512 + t] (uint4) = f16 W1[t][8k4..8k4+7]   (k4 in [0,32))
// WZP[k4*512 + t] (uint4) = f16 WZ[t][8k4..8k4+7]   (k4 in [0,24)),
//   WZ[t][c] = c<64 ? Wih[t][c] : Whh[t][c-64]
__global__ __launch_bounds__(256) void pack_kernel(
    const float* __restrict__ W1, const float* __restrict__ Wih,
    const float* __restrict__ Whh, const float* __restrict__ bih,
    const float* __restrict__ bhh, uint4* __restrict__ W1P,
    uint4* __restrict__ WZP, float* __restrict__ bz) {
  int gid = blockIdx.x * 256 + threadIdx.x;
  if (gid < 512) bz[gid] = bih[gid] + bhh[gid];
  if (gid < 16384) {
    int k4 = gid >> 9, t = gid & 511;
    const float* src = W1 + t * 256 + k4 * 8;
    uint4 o;
    o.x = pack2(src[0], src[1]);
    o.y = pack2(src[2], src[3]);
    o.z = pack2(src[4], src[5]);
    o.w = pack2(src[6], src[7]);
    W1P[gid] = o;
  } else if (gid < 28672) {
    int g = gid - 16384;
    int k4 = g >> 9, t = g & 511;
    float v[8];
#pragma unroll
    for (int q = 0; q < 8; ++q) {
      int col = k4 * 8 + q;
      v[q] = (col < 64) ? Wih[t * 64 + col] : Whh[t * 128 + col - 64];
    }
    uint4 o;
    o.x = pack2(v[0], v[1]);
    o.y = pack2(v[2], v[3]);
    o.z = pack2(v[4], v[5]);
    o.w = pack2(v[6], v[7]);
    WZP[g] = o;
  }
}

// ---- s2 = einsum('btd,st->bds') + b2 --------------------------------------
__global__ __launch_bounds__(256) void s2_kernel(
    const float* __restrict__ X, const float* __restrict__ W2,
    const float* __restrict__ b2, float* __restrict__ s2) {
  __shared__ float Xs[64 * 68];
  __shared__ float W2sT[64 * 68];
  const int b = blockIdx.y;
  const int s0 = blockIdx.x * 64;
  const int tid = threadIdx.x;
  const int dq = tid & 15, sq = tid >> 4;
  float acc[4][4] = {{0.f, 0.f, 0.f, 0.f}};

  for (int t0 = 0; t0 < 512; t0 += 64) {
    __syncthreads();
    for (int i = tid; i < 4096; i += 256) {
      int tt = i >> 6, dd = i & 63;
      Xs[tt * 68 + dd] = X[((size_t)b * 512 + t0 + tt) * 64 + dd];
      int ss = i >> 6, t2 = i & 63;
      W2sT[t2 * 68 + ss] = W2[(size_t)(s0 + ss) * 512 + t0 + t2];
    }
    __syncthreads();
    const float4* Xs4 = (const float4*)Xs;
    const float4* W4 = (const float4*)W2sT;
#pragma unroll 8
    for (int tt = 0; tt < 64; ++tt) {
      float4 xv = Xs4[tt * 17 + dq];
      float4 wv = W4[tt * 17 + sq];
      float xa[4] = {xv.x, xv.y, xv.z, xv.w};
      float wa[4] = {wv.x, wv.y, wv.z, wv.w};
#pragma unroll
      for (int q = 0; q < 4; ++q)
#pragma unroll
        for (int r = 0; r < 4; ++r) acc[q][r] += xa[q] * wa[r];
    }
  }
  const float* bp = b2 + s0 + sq * 4;
  float b0 = bp[0], bx1 = bp[1], bx2 = bp[2], bx3 = bp[3];
#pragma unroll
  for (int q = 0; q < 4; ++q) {
    float4 o = make_float4(acc[q][0] + b0, acc[q][1] + bx1,
                           acc[q][2] + bx2, acc[q][3] + bx3);
    *(float4*)&s2[((size_t)b * 64 + dq * 4 + q) * 512 + s0 + sq * 4] = o;
  }
}

// ---- the recurrence -------------------------------------------------------
// grid 256 (one block per b), 1024 threads (16 waves).
__global__ __launch_bounds__(1024) void rnn_kernel(
    const float* __restrict__ X, const float* __restrict__ s2g,
    const uint4* __restrict__ W1P, const uint4* __restrict__ WZP,
    const float* __restrict__ b1, const float* __restrict__ bz,
    const float* __restrict__ W3, float* __restrict__ out) {
  __shared__ float4 s2s4[64 * 128];  // 128 KB: SCALE2*s2[b], row d = 512 f32
  __shared__ uint4 hcp4[32];         // packed f16: h pairs (16) + c pairs (16)
  __shared__ uint4 xp4[8];           // packed f16: x pairs
  __shared__ float cbuf[128];        // c state, f32
  __shared__ float4 part4[256];      // split-k partials (1024 f32)
  __shared__ float4 w3s4[128];       // -2*w3 (512)
  __shared__ float eb[64];

  unsigned* hcp = (unsigned*)hcp4;
  unsigned* xp = (unsigned*)xp4;
  float* part = (float*)part4;
  float* w3s = (float*)w3s4;

  const int bb = blockIdx.x;
  const int tid = threadIdx.x;
  const int lane = tid & 63;
  const int w = tid >> 6;        // wave 0..15
  const int r = tid & 511;       // output row
  const int hh = tid >> 9;       // k-half (0/1)

  // ---- stage SCALE2*s2[b] into LDS ----
  {
    const float4* src = (const float4*)(s2g + (size_t)bb * 32768);
    for (int i = tid; i < 8192; i += 1024) {
      float4 v = src[i];
      s2s4[i] = make_float4(SCALE2F * v.x, SCALE2F * v.y,
                            SCALE2F * v.z, SCALE2F * v.w);
    }
  }
  if (tid < 32) hcp4[tid] = make_uint4(0u, 0u, 0u, 0u);
  if (tid < 128) cbuf[tid] = 0.f;
  if (tid < 512) w3s[tid] = -2.f * W3[tid];
  const float b1r = b1[r];
  const float bzr = bz[r];
  float xpre = X[((size_t)bb * 512 + 0) * 64 + lane];
  __syncthreads();

  for (int t = 0; t < 512; ++t) {
    // Opaque zero offset: loop-variant address -> LICM cannot hoist weight
    // loads (round 4-8 lesson: hoist -> 224 live regs -> spill -> 37 GB HBM).
    unsigned zoff = 0;
    asm volatile("" : "+v"(zoff));
    const uint4* wp = W1P + r + zoff;
    const uint4* wq = WZP + r + zoff;

    // ---- phase 1 (split-k): part[tid] = SCALE2*(b1 + [h;c].W1row half) ----
    {
      float a0 = hh ? 0.f : b1r, a1 = 0.f, a2 = 0.f, a3 = 0.f;
      const int base = hh << 4;  // uint4 index of this half (16 per half)
#define P1G(OFF) {                                                  \
      const uint4 q0 = wp[((OFF) + 0) * 512];                       \
      const uint4 q1 = wp[((OFF) + 1) * 512];                       \
      const uint4 q2 = wp[((OFF) + 2) * 512];                       \
      const uint4 q3 = wp[((OFF) + 3) * 512];                       \
      const uint4 q4 = wp[((OFF) + 4) * 512];                       \
      const uint4 q5 = wp[((OFF) + 5) * 512];                       \
      const uint4 q6 = wp[((OFF) + 6) * 512];                       \
      const uint4 q7 = wp[((OFF) + 7) * 512];                       \
      a0 = dot4q(q0, hcp4[(OFF) + 0], a0);                          \
      a1 = dot4q(q1, hcp4[(OFF) + 1], a1);                          \
      a2 = dot4q(q2, hcp4[(OFF) + 2], a2);                          \
      a3 = dot4q(q3, hcp4[(OFF) + 3], a3);                          \
      a0 = dot4q(q4, hcp4[(OFF) + 4], a0);                          \
      a1 = dot4q(q5, hcp4[(OFF) + 5], a1);                          \
      a2 = dot4q(q6, hcp4[(OFF) + 6], a2);                          \
      a3 = dot4q(q7, hcp4[(OFF) + 7], a3);                          \
    }
      P1G(base) P1G(base + 8)
      part[tid] = SCALE2F * ((a0 + a1) + (a2 + a3));
    }
    __syncthreads();

    // ---- phase 2: eb[d] = sum_t (-2*w3)*rcp(exp2(s1s+s2s)+1) ----
    {
      float e0 = 0.f, e1 = 0.f, e2 = 0.f, e3 = 0.f;
#define P2D(DD, L) {                                                \
      const float4 s2v = rowp[(DD) * 2048];                         \
      L = fmaf(wv.x, __builtin_amdgcn_rcpf(                         \
              exp2f(sv.x + s2v.x) + 1.f), L);                       \
      L = fmaf(wv.y, __builtin_amdgcn_rcpf(                         \
              exp2f(sv.y + s2v.y) + 1.f), L);                       \
      L = fmaf(wv.z, __builtin_amdgcn_rcpf(                         \
              exp2f(sv.z + s2v.z) + 1.f), L);                       \
      L = fmaf(wv.w, __builtin_amdgcn_rcpf(                         \
              exp2f(sv.w + s2v.w) + 1.f), L);                       \
    }
#pragma unroll
      for (int i = 0; i < 2; ++i) {
        const int f4 = lane + 64 * i;
        const float4 pa = part4[f4];
        const float4 pb = part4[128 + f4];
        const float4 sv = make_float4(pa.x + pb.x, pa.y + pb.y,
                                      pa.z + pb.z, pa.w + pb.w);
        const float4 wv = w3s4[f4];
        const float4* rowp = &s2s4[w * 128 + f4];
        P2D(0, e0) P2D(1, e1) P2D(2, e2) P2D(3, e3)
      }
#define P2R(DD, L) {                                                \
      float local = L;                                              \
      _Pragma("unroll")                                             \
      for (int off = 32; off; off >>= 1)                            \
        local += __shfl_xor(local, off);                            \
      if (lane == 0) eb[w + 16 * (DD)] = local;                     \
    }
      P2R(0, e0) P2R(1, e1) P2R(2, e2) P2R(3, e3)
    }
    __syncthreads();

    // ---- phase 3: softmax over d + x = a*x_t, ALL waves redundantly ----
    {
      float e = eb[lane];
      float m = e;
#pragma unroll
      for (int off = 32; off; off >>= 1) m = fmaxf(m, __shfl_xor(m, off));
      float p = __expf(e - m);
      float s = p;
#pragma unroll
      for (int off = 32; off; off >>= 1) s += __shfl_xor(s, off);
      float xv = __builtin_amdgcn_rcpf(s) * p * xpre;
      float xo = __shfl_xor(xv, 1);
      if (!(lane & 1)) xp[lane >> 1] = pack2(xv, xo);
      int tn = (t + 1 < 512) ? t + 1 : 511;
      xpre = X[((size_t)bb * 512 + tn) * 64 + lane];
    }
    // no barrier: each wave wrote the (identical) xp values it reads next.

    // ---- phase 4 (split-k): part[tid] = (bz +) [x;h].WZrow half ----
    {
      float z0 = hh ? 0.f : bzr, z1 = 0.f, z2 = 0.f, z3 = 0.f;
      const int zbase = hh * 12;
#define P4A(K) (((K) < 8) ? xp4[K] : hcp4[(K) - 8])
#define P4G8(OFF) {                                                 \
      const uint4 q0 = wq[((OFF) + 0) * 512];                       \
      const uint4 q1 = wq[((OFF) + 1) * 512];                       \
      const uint4 q2 = wq[((OFF) + 2) * 512];                       \
      const uint4 q3 = wq[((OFF) + 3) * 512];                       \
      const uint4 q4 = wq[((OFF) + 4) * 512];                       \
      const uint4 q5 = wq[((OFF) + 5) * 512];                       \
      const uint4 q6 = wq[((OFF) + 6) * 512];                       \
      const uint4 q7 = wq[((OFF) + 7) * 512];                       \
      z0 = dot4q(q0, P4A((OFF) + 0), z0);                           \
      z1 = dot4q(q1, P4A((OFF) + 1), z1);                           \
      z2 = dot4q(q2, P4A((OFF) + 2), z2);                           \
      z3 = dot4q(q3, P4A((OFF) + 3), z3);                           \
      z0 = dot4q(q4, P4A((OFF) + 4), z0);                           \
      z1 = dot4q(q5, P4A((OFF) + 5), z1);                           \
      z2 = dot4q(q6, P4A((OFF) + 6), z2);                           \
      z3 = dot4q(q7, P4A((OFF) + 7), z3);                           \
    }
#define P4G4(OFF) {                                                 \
      const uint4 q0 = wq[((OFF) + 0) * 512];                       \
      const uint4 q1 = wq[((OFF) + 1) * 512];                       \
      const uint4 q2 = wq[((OFF) + 2) * 512];                       \
      const uint4 q3 = wq[((OFF) + 3) * 512];                       \
      z0 = dot4q(q0, P4A((OFF) + 0), z0);                           \
      z1 = dot4q(q1, P4A((OFF) + 1), z1);                           \
      z2 = dot4q(q2, P4A((OFF) + 2), z2);                           \
      z3 = dot4q(q3, P4A((OFF) + 3), z3);                           \
    }
      P4G8(zbase) P4G4(zbase + 8)
      part[tid] = (z0 + z1) + (z2 + z3);
    }
    __syncthreads();

    // ---- phase 5: LSTM gates (tid<128), write h, pack f16 state ----
    if (tid < 128) {
      float zi = part[tid] + part[tid + 512];
      float zf = part[tid + 128] + part[tid + 640];
      float zg = part[tid + 256] + part[tid + 768];
      float zo = part[tid + 384] + part[tid + 896];
      float c = cbuf[tid];
      float cn = sigm(zf) * c + sigm(zi) * tanh_fast(zg);
      float hn = sigm(zo) * tanh_fast(cn);
      cbuf[tid] = cn;
      out[((size_t)bb * 512 + t) * 128 + tid] = hn;
      float hp = __shfl_xor(hn, 1);
      float cp = __shfl_xor(cn, 1);
      if (!(tid & 1)) {
        hcp[tid >> 1] = pack2(hn, hp);
        hcp[64 + (tid >> 1)] = pack2(cn, cp);
      }
    }
    __syncthreads();
  }
}

extern "C" void kernel_launch(void* const* d_in, const int* in_sizes, int n_in,
                              void* d_out, int out_size, void* d_ws, size_t ws_size,
                              hipStream_t stream) {
  const float* X   = (const float*)d_in[0];
  const float* Wih = (const float*)d_in[1];
  const float* Whh = (const float*)d_in[2];
  const float* bih = (const float*)d_in[3];
  const float* bhh = (const float*)d_in[4];
  const float* W1  = (const float*)d_in[5];
  const float* b1  = (const float*)d_in[6];
  const float* W2  = (const float*)d_in[7];
  const float* b2  = (const float*)d_in[8];
  const float* W3  = (const float*)d_in[9];
  float* out = (float*)d_out;
  float* ws = (float*)d_ws;

  float* s2  = ws;                               // 8,388,608 f32 (32 MB)
  uint4* W1P = (uint4*)(ws + 8388608);           // 16384 uint4 (256 KB)
  uint4* WZP = (uint4*)(ws + 8388608 + 65536);   // 12288 uint4 (192 KB)
  float* bz  = ws + 8388608 + 65536 + 49152;     // 512 f32

  hipLaunchKernelGGL(pack_kernel, dim3(112), dim3(256), 0, stream,
                     W1, Wih, Whh, bih, bhh, W1P, WZP, bz);
  hipLaunchKernelGGL(s2_kernel, dim3(8, 256), dim3(256), 0, stream,
                     X, W2, b2, s2);
  hipLaunchKernelGGL(rnn_kernel, dim3(256), dim3(1024), 0, stream,
                     X, s2, W1P, WZP, b1, bz, W3, out);
}